// Round 1
// baseline (532.238 us; speedup 1.0000x reference)
//
#include <hip/hip_runtime.h>

#define K_OFF   27
#define M_PAIRS 60000
#define C_DIM   64
#define N_OUT_C 125000
#define BN_EPS  1e-5f
#define CHUNKS  57   // blocks per offset k; 27*57 = 1539 blocks, 4 waves each

// ---------------------------------------------------------------------------
// Kernel 1: scatter conv. One wave per kernel-map entry (looped).
// lane = output channel d. W[k] column in VGPRs; x row via wave-uniform
// scalar loads; one wave-wide 256B atomicAdd per entry.
// ---------------------------------------------------------------------------
__global__ __launch_bounds__(256, 6) void conv_scatter(
    const float* __restrict__ x, const float* __restrict__ W,
    const int* __restrict__ in_idx, const int* __restrict__ out_idx,
    float* __restrict__ out)
{
    const int k     = blockIdx.x / CHUNKS;
    const int chunk = blockIdx.x % CHUNKS;
    const int wave  = threadIdx.x >> 6;
    const int lane  = threadIdx.x & 63;
    const int wid   = chunk * 4 + wave;       // wave id within this k
    const int WSTEP = CHUNKS * 4;             // 228 waves per k

    // Load this lane's W column for offset k: wcol[c] = W[k][c][lane].
    // 64 coalesced 256B wave-loads, amortized over ~263 entries.
    float wcol[C_DIM];
    const float* Wk = W + (size_t)k * C_DIM * C_DIM;
#pragma unroll
    for (int c = 0; c < C_DIM; ++c) wcol[c] = Wk[c * C_DIM + lane];

    const int kbase = k * M_PAIRS;
    for (int m = wid; m < M_PAIRS; m += WSTEP) {
        int ii = in_idx[kbase + m];   // all lanes same addr -> 1 transaction
        int oi = out_idx[kbase + m];
        ii = __builtin_amdgcn_readfirstlane(ii);   // force SGPR -> s_load path
        oi = __builtin_amdgcn_readfirstlane(oi);

        const float* xr = (const float*)__builtin_assume_aligned(
            x + (size_t)ii * C_DIM, 256);

        float a0 = 0.f, a1 = 0.f, a2 = 0.f, a3 = 0.f;
#pragma unroll
        for (int c = 0; c < C_DIM; c += 4) {
            a0 = fmaf(xr[c + 0], wcol[c + 0], a0);
            a1 = fmaf(xr[c + 1], wcol[c + 1], a1);
            a2 = fmaf(xr[c + 2], wcol[c + 2], a2);
            a3 = fmaf(xr[c + 3], wcol[c + 3], a3);
        }
        float acc = (a0 + a1) + (a2 + a3);

        atomicAdd(out + (size_t)oi * C_DIM + lane, acc);  // 256B contiguous
    }
}

// ---------------------------------------------------------------------------
// Kernel 2: BN stats. stats[0..63] = per-channel sum, [64..127] = sumsq.
// ---------------------------------------------------------------------------
__global__ __launch_bounds__(256) void bn_stats(
    const float* __restrict__ acc, float* __restrict__ stats)
{
    const int tid = blockIdx.x * blockDim.x + threadIdx.x;
    const int T   = gridDim.x * blockDim.x;          // multiple of 16
    const int cq  = (tid & 15) * 4;                  // this thread's channel quad
    const int total4 = N_OUT_C * C_DIM / 4;

    float s0 = 0, s1 = 0, s2 = 0, s3 = 0;
    float q0 = 0, q1 = 0, q2 = 0, q3 = 0;
    const float4* a4 = (const float4*)acc;
    for (int i = tid; i < total4; i += T) {
        float4 v = a4[i];
        s0 += v.x; q0 = fmaf(v.x, v.x, q0);
        s1 += v.y; q1 = fmaf(v.y, v.y, q1);
        s2 += v.z; q2 = fmaf(v.z, v.z, q2);
        s3 += v.w; q3 = fmaf(v.w, v.w, q3);
    }

    __shared__ float ls[128];
    if (threadIdx.x < 128) ls[threadIdx.x] = 0.f;
    __syncthreads();
    atomicAdd(&ls[cq + 0], s0); atomicAdd(&ls[cq + 1], s1);
    atomicAdd(&ls[cq + 2], s2); atomicAdd(&ls[cq + 3], s3);
    atomicAdd(&ls[64 + cq + 0], q0); atomicAdd(&ls[64 + cq + 1], q1);
    atomicAdd(&ls[64 + cq + 2], q2); atomicAdd(&ls[64 + cq + 3], q3);
    __syncthreads();
    if (threadIdx.x < 128) atomicAdd(&stats[threadIdx.x], ls[threadIdx.x]);
}

// ---------------------------------------------------------------------------
// Kernel 3: in-place normalize. Each block folds mean/var -> scale/shift.
// ---------------------------------------------------------------------------
__global__ __launch_bounds__(256) void bn_apply(
    float* __restrict__ out, const float* __restrict__ stats,
    const float* __restrict__ gamma, const float* __restrict__ beta)
{
    __shared__ float ssc[C_DIM], ssh[C_DIM];
    if (threadIdx.x < C_DIM) {
        const float inv_n = 1.0f / (float)N_OUT_C;
        float mean = stats[threadIdx.x] * inv_n;
        float var  = stats[C_DIM + threadIdx.x] * inv_n - mean * mean;
        float inv  = rsqrtf(var + BN_EPS);
        float s    = inv * gamma[threadIdx.x];
        ssc[threadIdx.x] = s;
        ssh[threadIdx.x] = beta[threadIdx.x] - mean * s;
    }
    __syncthreads();

    const int tid = blockIdx.x * blockDim.x + threadIdx.x;
    const int T   = gridDim.x * blockDim.x;          // multiple of 16
    const int cq  = (tid & 15) * 4;
    const int total4 = N_OUT_C * C_DIM / 4;

    const float4 sc = make_float4(ssc[cq], ssc[cq + 1], ssc[cq + 2], ssc[cq + 3]);
    const float4 sh = make_float4(ssh[cq], ssh[cq + 1], ssh[cq + 2], ssh[cq + 3]);

    float4* o4 = (float4*)out;
    for (int i = tid; i < total4; i += T) {
        float4 v = o4[i];
        v.x = fmaf(v.x, sc.x, sh.x);
        v.y = fmaf(v.y, sc.y, sh.y);
        v.z = fmaf(v.z, sc.z, sh.z);
        v.w = fmaf(v.w, sc.w, sh.w);
        o4[i] = v;
    }
}

// ---------------------------------------------------------------------------
extern "C" void kernel_launch(void* const* d_in, const int* in_sizes, int n_in,
                              void* d_out, int out_size, void* d_ws, size_t ws_size,
                              hipStream_t stream)
{
    const float* x       = (const float*)d_in[0];
    const float* W       = (const float*)d_in[1];
    const float* gamma   = (const float*)d_in[2];
    const float* beta    = (const float*)d_in[3];
    const int*   in_idx  = (const int*)d_in[4];
    const int*   out_idx = (const int*)d_in[5];
    float* out   = (float*)d_out;
    float* stats = (float*)d_ws;   // 128 floats

    // Zero the accumulator (d_out doubles as pre-BN accumulator) and stats.
    hipMemsetAsync(out, 0, (size_t)N_OUT_C * C_DIM * sizeof(float), stream);
    hipMemsetAsync(stats, 0, 128 * sizeof(float), stream);

    conv_scatter<<<K_OFF * CHUNKS, 256, 0, stream>>>(x, W, in_idx, out_idx, out);
    bn_stats   <<<512, 256, 0, stream>>>(out, stats);
    bn_apply   <<<1024, 256, 0, stream>>>(out, stats, gamma, beta);
}

// Round 2
// 457.290 us; speedup vs baseline: 1.1639x; 1.1639x over previous
//
#include <hip/hip_runtime.h>

#define K_OFF   27
#define M_PAIRS 60000
#define C_DIM   64
#define N_OUT_C 125000
#define BN_EPS  1e-5f
#define CHUNKS  38   // blocks per offset k; 27*38 = 1026 blocks ~= 4/CU resident

// ---------------------------------------------------------------------------
// Kernel 1: scatter conv. One wave per kernel-map entry (looped).
// lane = output channel d. W[k] column held in 64 VGPRs (launch_bounds(256,4)
// gives the allocator a 128-VGPR budget so it is NOT demoted); x row via
// wave-uniform s_load (readfirstlane); one wave-wide 256B HW atomic per entry.
// ---------------------------------------------------------------------------
__global__ __launch_bounds__(256, 4) void conv_scatter(
    const float* __restrict__ x, const float* __restrict__ W,
    const int* __restrict__ in_idx, const int* __restrict__ out_idx,
    float* __restrict__ out)
{
    const int k     = blockIdx.x / CHUNKS;
    const int chunk = blockIdx.x % CHUNKS;
    const int wave  = threadIdx.x >> 6;
    const int lane  = threadIdx.x & 63;
    const int wid   = chunk * 4 + wave;       // wave id within this k
    const int WSTEP = CHUNKS * 4;             // 152 waves per k

    // Load this lane's W column for offset k: wcol[c] = W[k][c][lane].
    // 64 coalesced 256B wave-loads, amortized over ~395 entries.
    float wcol[C_DIM];
    const float* Wk = W + (size_t)k * C_DIM * C_DIM;
#pragma unroll
    for (int c = 0; c < C_DIM; ++c) wcol[c] = Wk[c * C_DIM + lane];

    const int kbase = k * M_PAIRS;
    for (int m = wid; m < M_PAIRS; m += WSTEP) {
        int ii = in_idx[kbase + m];   // wave-uniform -> 1 transaction
        int oi = out_idx[kbase + m];
        ii = __builtin_amdgcn_readfirstlane(ii);   // force SGPR -> s_load path
        oi = __builtin_amdgcn_readfirstlane(oi);

        const float* xr = (const float*)__builtin_assume_aligned(
            x + (size_t)ii * C_DIM, 256);

        float a0 = 0.f, a1 = 0.f, a2 = 0.f, a3 = 0.f;
#pragma unroll
        for (int c = 0; c < C_DIM; c += 4) {
            a0 = fmaf(xr[c + 0], wcol[c + 0], a0);
            a1 = fmaf(xr[c + 1], wcol[c + 1], a1);
            a2 = fmaf(xr[c + 2], wcol[c + 2], a2);
            a3 = fmaf(xr[c + 3], wcol[c + 3], a3);
        }
        float acc = (a0 + a1) + (a2 + a3);

        // HW global_atomic_add_f32 (no CAS loop, no return). 256B contiguous.
        unsafeAtomicAdd(out + (size_t)oi * C_DIM + lane, acc);
    }
}

// ---------------------------------------------------------------------------
// Kernel 2: BN stats. stats[0..63] = per-channel sum, [64..127] = sumsq.
// ---------------------------------------------------------------------------
__global__ __launch_bounds__(256) void bn_stats(
    const float* __restrict__ acc, float* __restrict__ stats)
{
    const int tid = blockIdx.x * blockDim.x + threadIdx.x;
    const int T   = gridDim.x * blockDim.x;          // multiple of 16
    const int cq  = (tid & 15) * 4;                  // this thread's channel quad
    const int total4 = N_OUT_C * C_DIM / 4;

    float s0 = 0, s1 = 0, s2 = 0, s3 = 0;
    float q0 = 0, q1 = 0, q2 = 0, q3 = 0;
    const float4* a4 = (const float4*)acc;
    for (int i = tid; i < total4; i += T) {
        float4 v = a4[i];
        s0 += v.x; q0 = fmaf(v.x, v.x, q0);
        s1 += v.y; q1 = fmaf(v.y, v.y, q1);
        s2 += v.z; q2 = fmaf(v.z, v.z, q2);
        s3 += v.w; q3 = fmaf(v.w, v.w, q3);
    }

    __shared__ float ls[128];
    if (threadIdx.x < 128) ls[threadIdx.x] = 0.f;
    __syncthreads();
    atomicAdd(&ls[cq + 0], s0); atomicAdd(&ls[cq + 1], s1);
    atomicAdd(&ls[cq + 2], s2); atomicAdd(&ls[cq + 3], s3);
    atomicAdd(&ls[64 + cq + 0], q0); atomicAdd(&ls[64 + cq + 1], q1);
    atomicAdd(&ls[64 + cq + 2], q2); atomicAdd(&ls[64 + cq + 3], q3);
    __syncthreads();
    if (threadIdx.x < 128) unsafeAtomicAdd(&stats[threadIdx.x], ls[threadIdx.x]);
}

// ---------------------------------------------------------------------------
// Kernel 3: in-place normalize. Each block folds mean/var -> scale/shift.
// ---------------------------------------------------------------------------
__global__ __launch_bounds__(256) void bn_apply(
    float* __restrict__ out, const float* __restrict__ stats,
    const float* __restrict__ gamma, const float* __restrict__ beta)
{
    __shared__ float ssc[C_DIM], ssh[C_DIM];
    if (threadIdx.x < C_DIM) {
        const float inv_n = 1.0f / (float)N_OUT_C;
        float mean = stats[threadIdx.x] * inv_n;
        float var  = stats[C_DIM + threadIdx.x] * inv_n - mean * mean;
        float inv  = rsqrtf(var + BN_EPS);
        float s    = inv * gamma[threadIdx.x];
        ssc[threadIdx.x] = s;
        ssh[threadIdx.x] = beta[threadIdx.x] - mean * s;
    }
    __syncthreads();

    const int tid = blockIdx.x * blockDim.x + threadIdx.x;
    const int T   = gridDim.x * blockDim.x;          // multiple of 16
    const int cq  = (tid & 15) * 4;
    const int total4 = N_OUT_C * C_DIM / 4;

    const float4 sc = make_float4(ssc[cq], ssc[cq + 1], ssc[cq + 2], ssc[cq + 3]);
    const float4 sh = make_float4(ssh[cq], ssh[cq + 1], ssh[cq + 2], ssh[cq + 3]);

    float4* o4 = (float4*)out;
    for (int i = tid; i < total4; i += T) {
        float4 v = o4[i];
        v.x = fmaf(v.x, sc.x, sh.x);
        v.y = fmaf(v.y, sc.y, sh.y);
        v.z = fmaf(v.z, sc.z, sh.z);
        v.w = fmaf(v.w, sc.w, sh.w);
        o4[i] = v;
    }
}

// ---------------------------------------------------------------------------
extern "C" void kernel_launch(void* const* d_in, const int* in_sizes, int n_in,
                              void* d_out, int out_size, void* d_ws, size_t ws_size,
                              hipStream_t stream)
{
    const float* x       = (const float*)d_in[0];
    const float* W       = (const float*)d_in[1];
    const float* gamma   = (const float*)d_in[2];
    const float* beta    = (const float*)d_in[3];
    const int*   in_idx  = (const int*)d_in[4];
    const int*   out_idx = (const int*)d_in[5];
    float* out   = (float*)d_out;
    float* stats = (float*)d_ws;   // 128 floats

    // Zero the accumulator (d_out doubles as pre-BN accumulator) and stats.
    hipMemsetAsync(out, 0, (size_t)N_OUT_C * C_DIM * sizeof(float), stream);
    hipMemsetAsync(stats, 0, 128 * sizeof(float), stream);

    conv_scatter<<<K_OFF * CHUNKS, 256, 0, stream>>>(x, W, in_idx, out_idx, out);
    bn_stats   <<<512, 256, 0, stream>>>(out, stats);
    bn_apply   <<<1024, 256, 0, stream>>>(out, stats, gamma, beta);
}

// Round 3
// 445.134 us; speedup vs baseline: 1.1957x; 1.0273x over previous
//
#include <hip/hip_runtime.h>

#define K_OFF   27
#define M_PAIRS 60000
#define C_DIM   64
#define N_OUT_C 125000
#define BN_EPS  1e-5f
#define CHUNKS  37                 // 27*37 = 999 blocks <= 1024 co-resident (4/CU)
#define WAVES_PER_K (CHUNKS * 4)   // 148 waves per offset k
#define SPAN ((M_PAIRS + WAVES_PER_K - 1) / WAVES_PER_K)  // 406 entries/wave

// ---------------------------------------------------------------------------
// Kernel 1: scatter conv. One wave per kernel-map entry (contiguous span).
// lane = output channel d. W[k] column PINNED in 64 VGPRs via opaque asm
// (round-2 showed launch_bounds alone doesn't stop rematerialization:
// VGPR_Count stayed 40). x row arrives via wave-uniform s_load into SGPRs
// (SGPR_Count=96 confirmed that path). One wave-wide 256B HW atomic per entry.
// ---------------------------------------------------------------------------
__global__ __launch_bounds__(256, 4) void conv_scatter(
    const float* __restrict__ x, const float* __restrict__ W,
    const int* __restrict__ in_idx, const int* __restrict__ out_idx,
    float* __restrict__ out)
{
    const int k     = blockIdx.x / CHUNKS;
    const int chunk = blockIdx.x % CHUNKS;
    const int wave  = threadIdx.x >> 6;
    const int lane  = threadIdx.x & 63;
    const int wid   = chunk * 4 + wave;

    // Load this lane's W column for offset k: wcol[c] = W[k][c][lane].
    float wcol[C_DIM];
    const float* Wk = W + (size_t)k * C_DIM * C_DIM;
#pragma unroll
    for (int c = 0; c < C_DIM; ++c) wcol[c] = Wk[c * C_DIM + lane];
    // Opaque to the optimizer: forces all 64 values to be materialized in
    // VGPRs here and NEVER re-loaded inside the m-loop.
#pragma unroll
    for (int c = 0; c < C_DIM; ++c) asm volatile("" : "+v"(wcol[c]));

    const int kbase = k * M_PAIRS;
    const int m0 = wid * SPAN;
    const int m1 = (m0 + SPAN < M_PAIRS) ? m0 + SPAN : M_PAIRS;

    for (int m = m0; m < m1; ++m) {
        // Sequential per-wave -> scalar-cache line reused 15/16 times.
        int ii = __builtin_amdgcn_readfirstlane(in_idx[kbase + m]);
        int oi = __builtin_amdgcn_readfirstlane(out_idx[kbase + m]);

        const float* xr = (const float*)__builtin_assume_aligned(
            x + (size_t)ii * C_DIM, 256);

        float a0 = 0.f, a1 = 0.f, a2 = 0.f, a3 = 0.f;
#pragma unroll
        for (int c = 0; c < C_DIM; c += 4) {
            a0 = fmaf(xr[c + 0], wcol[c + 0], a0);
            a1 = fmaf(xr[c + 1], wcol[c + 1], a1);
            a2 = fmaf(xr[c + 2], wcol[c + 2], a2);
            a3 = fmaf(xr[c + 3], wcol[c + 3], a3);
        }
        float acc = (a0 + a1) + (a2 + a3);

        // HW global_atomic_add_f32, no return. 256B contiguous per wave.
        unsafeAtomicAdd(out + (size_t)oi * C_DIM + lane, acc);
    }
}

// ---------------------------------------------------------------------------
// Kernel 2: BN stats. stats[0..63] = per-channel sum, [64..127] = sumsq.
// ---------------------------------------------------------------------------
__global__ __launch_bounds__(256) void bn_stats(
    const float* __restrict__ acc, float* __restrict__ stats)
{
    const int tid = blockIdx.x * blockDim.x + threadIdx.x;
    const int T   = gridDim.x * blockDim.x;          // multiple of 16
    const int cq  = (tid & 15) * 4;                  // this thread's channel quad
    const int total4 = N_OUT_C * C_DIM / 4;

    float s0 = 0, s1 = 0, s2 = 0, s3 = 0;
    float q0 = 0, q1 = 0, q2 = 0, q3 = 0;
    const float4* a4 = (const float4*)acc;
    for (int i = tid; i < total4; i += T) {
        float4 v = a4[i];
        s0 += v.x; q0 = fmaf(v.x, v.x, q0);
        s1 += v.y; q1 = fmaf(v.y, v.y, q1);
        s2 += v.z; q2 = fmaf(v.z, v.z, q2);
        s3 += v.w; q3 = fmaf(v.w, v.w, q3);
    }

    __shared__ float ls[128];
    if (threadIdx.x < 128) ls[threadIdx.x] = 0.f;
    __syncthreads();
    atomicAdd(&ls[cq + 0], s0); atomicAdd(&ls[cq + 1], s1);
    atomicAdd(&ls[cq + 2], s2); atomicAdd(&ls[cq + 3], s3);
    atomicAdd(&ls[64 + cq + 0], q0); atomicAdd(&ls[64 + cq + 1], q1);
    atomicAdd(&ls[64 + cq + 2], q2); atomicAdd(&ls[64 + cq + 3], q3);
    __syncthreads();
    if (threadIdx.x < 128) unsafeAtomicAdd(&stats[threadIdx.x], ls[threadIdx.x]);
}

// ---------------------------------------------------------------------------
// Kernel 3: in-place normalize. Each block folds mean/var -> scale/shift.
// ---------------------------------------------------------------------------
__global__ __launch_bounds__(256) void bn_apply(
    float* __restrict__ out, const float* __restrict__ stats,
    const float* __restrict__ gamma, const float* __restrict__ beta)
{
    __shared__ float ssc[C_DIM], ssh[C_DIM];
    if (threadIdx.x < C_DIM) {
        const float inv_n = 1.0f / (float)N_OUT_C;
        float mean = stats[threadIdx.x] * inv_n;
        float var  = stats[C_DIM + threadIdx.x] * inv_n - mean * mean;
        float inv  = rsqrtf(var + BN_EPS);
        float s    = inv * gamma[threadIdx.x];
        ssc[threadIdx.x] = s;
        ssh[threadIdx.x] = beta[threadIdx.x] - mean * s;
    }
    __syncthreads();

    const int tid = blockIdx.x * blockDim.x + threadIdx.x;
    const int T   = gridDim.x * blockDim.x;          // multiple of 16
    const int cq  = (tid & 15) * 4;
    const int total4 = N_OUT_C * C_DIM / 4;

    const float4 sc = make_float4(ssc[cq], ssc[cq + 1], ssc[cq + 2], ssc[cq + 3]);
    const float4 sh = make_float4(ssh[cq], ssh[cq + 1], ssh[cq + 2], ssh[cq + 3]);

    float4* o4 = (float4*)out;
    for (int i = tid; i < total4; i += T) {
        float4 v = o4[i];
        v.x = fmaf(v.x, sc.x, sh.x);
        v.y = fmaf(v.y, sc.y, sh.y);
        v.z = fmaf(v.z, sc.z, sh.z);
        v.w = fmaf(v.w, sc.w, sh.w);
        o4[i] = v;
    }
}

// ---------------------------------------------------------------------------
extern "C" void kernel_launch(void* const* d_in, const int* in_sizes, int n_in,
                              void* d_out, int out_size, void* d_ws, size_t ws_size,
                              hipStream_t stream)
{
    const float* x       = (const float*)d_in[0];
    const float* W       = (const float*)d_in[1];
    const float* gamma   = (const float*)d_in[2];
    const float* beta    = (const float*)d_in[3];
    const int*   in_idx  = (const int*)d_in[4];
    const int*   out_idx = (const int*)d_in[5];
    float* out   = (float*)d_out;
    float* stats = (float*)d_ws;   // 128 floats

    // Zero the accumulator (d_out doubles as pre-BN accumulator) and stats.
    hipMemsetAsync(out, 0, (size_t)N_OUT_C * C_DIM * sizeof(float), stream);
    hipMemsetAsync(stats, 0, 128 * sizeof(float), stream);

    conv_scatter<<<K_OFF * CHUNKS, 256, 0, stream>>>(x, W, in_idx, out_idx, out);
    bn_stats   <<<512, 256, 0, stream>>>(out, stats);
    bn_apply   <<<1024, 256, 0, stream>>>(out, stats, gamma, beta);
}

// Round 4
// 410.846 us; speedup vs baseline: 1.2955x; 1.0835x over previous
//
#include <hip/hip_runtime.h>
#include <hip/hip_fp16.h>

typedef __attribute__((ext_vector_type(8))) short short8;
typedef __attribute__((ext_vector_type(4))) float f32x4;

#define K_OFF    27
#define M_PAIRS  60000
#define C_DIM    64
#define N_IN     500000
#define N_OUT_C  125000
#define BN_EPS   1e-5f

#define TILES_PER_K  ((M_PAIRS + 63) / 64)      // 938 (last tile: 32 valid rows)
#define TOTAL_WT     (K_OFF * TILES_PER_K)      // 25326 wave-tiles

// d_ws layout (fast path): [xb bf16 64MB][wt bf16 221KB][acc16 f16 16MB][stats 512B]
#define XB_BYTES ((size_t)N_IN * C_DIM * 2)             // 64,000,000
#define WT_OFF   XB_BYTES
#define WT_BYTES ((size_t)K_OFF * C_DIM * C_DIM * 2)    // 221,184
#define AC_OFF   (WT_OFF + WT_BYTES)
#define AC_BYTES ((size_t)N_OUT_C * C_DIM * 2)          // 16,000,000
#define ST_OFF   (AC_OFF + AC_BYTES)
#define WS_NEED  (ST_OFF + 512)

__device__ __forceinline__ unsigned short f32_to_bf16(float f) {
    unsigned u = __float_as_uint(f);
    u += 0x7FFFu + ((u >> 16) & 1u);          // RNE
    return (unsigned short)(u >> 16);
}

// ---------------------------------------------------------------------------
// x fp32 -> bf16 (one streaming pass)
// ---------------------------------------------------------------------------
__global__ __launch_bounds__(256) void conv_x(const float* __restrict__ x,
                                              unsigned short* __restrict__ xb) {
    const int tid = blockIdx.x * blockDim.x + threadIdx.x;
    const int T   = gridDim.x * blockDim.x;
    const int n4  = N_IN * C_DIM / 4;
    const float4* x4 = (const float4*)x;
    ushort4* b4 = (ushort4*)xb;
    for (int i = tid; i < n4; i += T) {
        float4 v = x4[i];
        ushort4 o;
        o.x = f32_to_bf16(v.x); o.y = f32_to_bf16(v.y);
        o.z = f32_to_bf16(v.z); o.w = f32_to_bf16(v.w);
        b4[i] = o;
    }
}

// ---------------------------------------------------------------------------
// W[k][c][d] fp32 -> wt[k][d][c] bf16 (B^T layout: MFMA b-frag = 16B contiguous)
// ---------------------------------------------------------------------------
__global__ __launch_bounds__(256) void conv_w(const float* __restrict__ W,
                                              unsigned short* __restrict__ wt) {
    const int tid = blockIdx.x * blockDim.x + threadIdx.x;
    if (tid >= K_OFF * C_DIM * C_DIM) return;
    const int c = tid & 63;
    const int d = (tid >> 6) & 63;
    const int k = tid >> 12;
    wt[tid] = f32_to_bf16(W[(k << 12) + (c << 6) + d]);
}

// ---------------------------------------------------------------------------
// Per (k, 64-row tile) wave: gather A-frags bf16 global->VGPR, B-frags in
// VGPRs (intrinsic operands), 32x mfma_16x16x32_bf16, scatter via
// global_atomic_pk_add_f16 (2 channels/op) into f16 accumulator.
// A layout: lane holds row=(l&15), k=(l>>4)*8+j. C/D: col=l&15, row=(l>>4)*4+reg.
// ---------------------------------------------------------------------------
__global__ __launch_bounds__(256, 3) void mfma_scatter(
    const unsigned short* __restrict__ xb, const unsigned short* __restrict__ wt,
    const int* __restrict__ in_idx, const int* __restrict__ out_idx,
    __half2* __restrict__ acc16)
{
    const int gwave = blockIdx.x * 4 + (threadIdx.x >> 6);
    if (gwave >= TOTAL_WT) return;
    const int lane = threadIdx.x & 63;
    const int lg = lane >> 4;            // 0..3
    const int lr = lane & 15;            // 0..15

    const int k  = gwave / TILES_PER_K;
    const int t  = gwave % TILES_PER_K;
    const int m0 = t * 64;
    const int kbase = k * M_PAIRS;

    // B fragments: bfr[ks][ct] lane holds wt[k][ct*16+lr][ks*32+lg*8 .. +8]
    short8 bfr[2][4];
    const unsigned short* wtk = wt + (size_t)k * C_DIM * C_DIM;
#pragma unroll
    for (int ks = 0; ks < 2; ++ks)
#pragma unroll
        for (int ct = 0; ct < 4; ++ct)
            bfr[ks][ct] = *(const short8*)(wtk + (ct * 16 + lr) * C_DIM + ks * 32 + lg * 8);

    // Row gather indices for A (this lane serves row rt*16+lr)
    int aidx[4];
#pragma unroll
    for (int rt = 0; rt < 4; ++rt) {
        const int m = m0 + rt * 16 + lr;
        aidx[rt] = (m < M_PAIRS) ? in_idx[kbase + m] : -1;
    }

    f32x4 acc[4][4] = {};

#pragma unroll
    for (int ks = 0; ks < 2; ++ks) {
#pragma unroll
        for (int rt = 0; rt < 4; ++rt) {
            short8 a = {};
            if (aidx[rt] >= 0)
                a = *(const short8*)(xb + (size_t)aidx[rt] * C_DIM + ks * 32 + lg * 8);
#pragma unroll
            for (int ct = 0; ct < 4; ++ct)
                acc[rt][ct] = __builtin_amdgcn_mfma_f32_16x16x32_bf16(
                    a, bfr[ks][ct], acc[rt][ct], 0, 0, 0);
        }
    }

    // Scatter: row m = m0 + rt*16 + lg*4 + j; channel d = ct*16 + lr.
    // Pair adjacent channels across lane pairs -> one pk_add_f16 per 2 ch.
#pragma unroll
    for (int rt = 0; rt < 4; ++rt) {
#pragma unroll
        for (int j = 0; j < 4; ++j) {
            const int m = m0 + rt * 16 + lg * 4 + j;
            int o = -1;
            if (m < M_PAIRS) o = out_idx[kbase + m];
#pragma unroll
            for (int ct = 0; ct < 4; ++ct) {
                float v0 = acc[rt][ct][j];
                float v1 = __shfl_xor(v0, 1);      // partner channel's value
                if (((lane & 1) == 0) && o >= 0) {
                    __half2 h = __floats2half2_rn(v0, v1);
                    unsafeAtomicAdd(acc16 + (size_t)o * 32 + (ct * 16 + lr) / 2, h);
                }
            }
        }
    }
}

// ---------------------------------------------------------------------------
// BN stats from f16 accumulator. stats[0..63]=sum, [64..127]=sumsq.
// ---------------------------------------------------------------------------
__global__ __launch_bounds__(256) void bn_stats_h2(
    const __half2* __restrict__ acc, float* __restrict__ stats)
{
    const int tid = blockIdx.x * blockDim.x + threadIdx.x;
    const int T   = gridDim.x * blockDim.x;
    const int q   = tid & 15;            // channels 4q..4q+3
    float s0=0,s1=0,s2=0,s3=0,p0=0,p1=0,p2=0,p3=0;
    for (int r = tid >> 4; r < N_OUT_C; r += (T >> 4)) {
        const __half2* p = acc + (size_t)r * 32 + 2 * q;
        float2 u = __half22float2(p[0]);
        float2 v = __half22float2(p[1]);
        s0 += u.x; p0 = fmaf(u.x, u.x, p0);
        s1 += u.y; p1 = fmaf(u.y, u.y, p1);
        s2 += v.x; p2 = fmaf(v.x, v.x, p2);
        s3 += v.y; p3 = fmaf(v.y, v.y, p3);
    }
    __shared__ float ls[128];
    if (threadIdx.x < 128) ls[threadIdx.x] = 0.f;
    __syncthreads();
    const int cq = q * 4;
    atomicAdd(&ls[cq + 0], s0); atomicAdd(&ls[cq + 1], s1);
    atomicAdd(&ls[cq + 2], s2); atomicAdd(&ls[cq + 3], s3);
    atomicAdd(&ls[64 + cq + 0], p0); atomicAdd(&ls[64 + cq + 1], p1);
    atomicAdd(&ls[64 + cq + 2], p2); atomicAdd(&ls[64 + cq + 3], p3);
    __syncthreads();
    if (threadIdx.x < 128) unsafeAtomicAdd(&stats[threadIdx.x], ls[threadIdx.x]);
}

// ---------------------------------------------------------------------------
// Normalize f16 accumulator -> f32 output.
// ---------------------------------------------------------------------------
__global__ __launch_bounds__(256) void bn_apply_h2(
    const __half2* __restrict__ acc, float* __restrict__ out,
    const float* __restrict__ stats, const float* __restrict__ gamma,
    const float* __restrict__ beta)
{
    __shared__ float ssc[C_DIM], ssh[C_DIM];
    if (threadIdx.x < C_DIM) {
        const float inv_n = 1.0f / (float)N_OUT_C;
        float mean = stats[threadIdx.x] * inv_n;
        float var  = stats[C_DIM + threadIdx.x] * inv_n - mean * mean;
        float inv  = rsqrtf(var + BN_EPS);
        float s    = inv * gamma[threadIdx.x];
        ssc[threadIdx.x] = s;
        ssh[threadIdx.x] = beta[threadIdx.x] - mean * s;
    }
    __syncthreads();

    const int tid = blockIdx.x * blockDim.x + threadIdx.x;
    const int T   = gridDim.x * blockDim.x;
    const int q   = tid & 15;
    const float4 sc = make_float4(ssc[4*q], ssc[4*q+1], ssc[4*q+2], ssc[4*q+3]);
    const float4 sh = make_float4(ssh[4*q], ssh[4*q+1], ssh[4*q+2], ssh[4*q+3]);

    for (int r = tid >> 4; r < N_OUT_C; r += (T >> 4)) {
        const __half2* p = acc + (size_t)r * 32 + 2 * q;
        float2 u = __half22float2(p[0]);
        float2 v = __half22float2(p[1]);
        float4 y;
        y.x = fmaf(u.x, sc.x, sh.x);
        y.y = fmaf(u.y, sc.y, sh.y);
        y.z = fmaf(v.x, sc.z, sh.z);
        y.w = fmaf(v.y, sc.w, sh.w);
        *(float4*)(out + (size_t)r * C_DIM + 4 * q) = y;
    }
}

// ===========================================================================
// Fallback path (ws too small): round-3 kernels, f32 atomics into d_out.
// ===========================================================================
#define FCHUNKS  37
#define FWPK     (FCHUNKS * 4)
#define FSPAN    ((M_PAIRS + FWPK - 1) / FWPK)

__global__ __launch_bounds__(256, 4) void conv_scatter(
    const float* __restrict__ x, const float* __restrict__ W,
    const int* __restrict__ in_idx, const int* __restrict__ out_idx,
    float* __restrict__ out)
{
    const int k     = blockIdx.x / FCHUNKS;
    const int chunk = blockIdx.x % FCHUNKS;
    const int wid   = chunk * 4 + (threadIdx.x >> 6);
    const int lane  = threadIdx.x & 63;

    float wcol[C_DIM];
    const float* Wk = W + (size_t)k * C_DIM * C_DIM;
#pragma unroll
    for (int c = 0; c < C_DIM; ++c) wcol[c] = Wk[c * C_DIM + lane];

    const int kbase = k * M_PAIRS;
    const int m0 = wid * FSPAN;
    const int m1 = (m0 + FSPAN < M_PAIRS) ? m0 + FSPAN : M_PAIRS;
    for (int m = m0; m < m1; ++m) {
        int ii = __builtin_amdgcn_readfirstlane(in_idx[kbase + m]);
        int oi = __builtin_amdgcn_readfirstlane(out_idx[kbase + m]);
        const float* xr = x + (size_t)ii * C_DIM;
        float a0=0.f,a1=0.f,a2=0.f,a3=0.f;
#pragma unroll
        for (int c = 0; c < C_DIM; c += 4) {
            a0 = fmaf(xr[c+0], wcol[c+0], a0);
            a1 = fmaf(xr[c+1], wcol[c+1], a1);
            a2 = fmaf(xr[c+2], wcol[c+2], a2);
            a3 = fmaf(xr[c+3], wcol[c+3], a3);
        }
        unsafeAtomicAdd(out + (size_t)oi * C_DIM + lane, (a0+a1)+(a2+a3));
    }
}

__global__ __launch_bounds__(256) void bn_stats_f32(
    const float* __restrict__ acc, float* __restrict__ stats)
{
    const int tid = blockIdx.x * blockDim.x + threadIdx.x;
    const int T   = gridDim.x * blockDim.x;
    const int cq  = (tid & 15) * 4;
    const int total4 = N_OUT_C * C_DIM / 4;
    float s0=0,s1=0,s2=0,s3=0,q0=0,q1=0,q2=0,q3=0;
    const float4* a4 = (const float4*)acc;
    for (int i = tid; i < total4; i += T) {
        float4 v = a4[i];
        s0+=v.x; q0=fmaf(v.x,v.x,q0);
        s1+=v.y; q1=fmaf(v.y,v.y,q1);
        s2+=v.z; q2=fmaf(v.z,v.z,q2);
        s3+=v.w; q3=fmaf(v.w,v.w,q3);
    }
    __shared__ float ls[128];
    if (threadIdx.x < 128) ls[threadIdx.x] = 0.f;
    __syncthreads();
    atomicAdd(&ls[cq+0],s0); atomicAdd(&ls[cq+1],s1);
    atomicAdd(&ls[cq+2],s2); atomicAdd(&ls[cq+3],s3);
    atomicAdd(&ls[64+cq+0],q0); atomicAdd(&ls[64+cq+1],q1);
    atomicAdd(&ls[64+cq+2],q2); atomicAdd(&ls[64+cq+3],q3);
    __syncthreads();
    if (threadIdx.x < 128) unsafeAtomicAdd(&stats[threadIdx.x], ls[threadIdx.x]);
}

__global__ __launch_bounds__(256) void bn_apply_f32(
    float* __restrict__ out, const float* __restrict__ stats,
    const float* __restrict__ gamma, const float* __restrict__ beta)
{
    __shared__ float ssc[C_DIM], ssh[C_DIM];
    if (threadIdx.x < C_DIM) {
        const float inv_n = 1.0f / (float)N_OUT_C;
        float mean = stats[threadIdx.x] * inv_n;
        float var  = stats[C_DIM + threadIdx.x] * inv_n - mean * mean;
        float inv  = rsqrtf(var + BN_EPS);
        float s    = inv * gamma[threadIdx.x];
        ssc[threadIdx.x] = s;
        ssh[threadIdx.x] = beta[threadIdx.x] - mean * s;
    }
    __syncthreads();
    const int tid = blockIdx.x * blockDim.x + threadIdx.x;
    const int T   = gridDim.x * blockDim.x;
    const int cq  = (tid & 15) * 4;
    const int total4 = N_OUT_C * C_DIM / 4;
    const float4 sc = make_float4(ssc[cq],ssc[cq+1],ssc[cq+2],ssc[cq+3]);
    const float4 sh = make_float4(ssh[cq],ssh[cq+1],ssh[cq+2],ssh[cq+3]);
    float4* o4 = (float4*)out;
    for (int i = tid; i < total4; i += T) {
        float4 v = o4[i];
        v.x = fmaf(v.x, sc.x, sh.x);
        v.y = fmaf(v.y, sc.y, sh.y);
        v.z = fmaf(v.z, sc.z, sh.z);
        v.w = fmaf(v.w, sc.w, sh.w);
        o4[i] = v;
    }
}

// ---------------------------------------------------------------------------
extern "C" void kernel_launch(void* const* d_in, const int* in_sizes, int n_in,
                              void* d_out, int out_size, void* d_ws, size_t ws_size,
                              hipStream_t stream)
{
    const float* x       = (const float*)d_in[0];
    const float* W       = (const float*)d_in[1];
    const float* gamma   = (const float*)d_in[2];
    const float* beta    = (const float*)d_in[3];
    const int*   in_idx  = (const int*)d_in[4];
    const int*   out_idx = (const int*)d_in[5];
    float* out = (float*)d_out;

    if (ws_size >= WS_NEED) {
        unsigned short* xb  = (unsigned short*)d_ws;
        unsigned short* wt  = (unsigned short*)((char*)d_ws + WT_OFF);
        __half2* acc16      = (__half2*)((char*)d_ws + AC_OFF);
        float* stats        = (float*)((char*)d_ws + ST_OFF);

        hipMemsetAsync(acc16, 0, AC_BYTES, stream);
        hipMemsetAsync(stats, 0, 128 * sizeof(float), stream);
        conv_x<<<2048, 256, 0, stream>>>(x, xb);
        conv_w<<<(K_OFF * C_DIM * C_DIM + 255) / 256, 256, 0, stream>>>(W, wt);
        mfma_scatter<<<(TOTAL_WT + 3) / 4, 256, 0, stream>>>(xb, wt, in_idx, out_idx, acc16);
        bn_stats_h2<<<512, 256, 0, stream>>>(acc16, stats);
        bn_apply_h2<<<1024, 256, 0, stream>>>(acc16, out, stats, gamma, beta);
    } else {
        float* stats = (float*)d_ws;
        hipMemsetAsync(out, 0, (size_t)N_OUT_C * C_DIM * sizeof(float), stream);
        hipMemsetAsync(stats, 0, 128 * sizeof(float), stream);
        conv_scatter<<<K_OFF * FCHUNKS, 256, 0, stream>>>(x, W, in_idx, out_idx, out);
        bn_stats_f32<<<512, 256, 0, stream>>>(out, stats);
        bn_apply_f32<<<1024, 256, 0, stream>>>(out, stats, gamma, beta);
    }
}